// Round 1
// baseline (353.586 us; speedup 1.0000x reference)
//
#include <hip/hip_runtime.h>

// RoPE: out[b,s,2k]   = c*x[b,s,2k] - s*x[b,s,2k+1]
//       out[b,s,2k+1] = s*x[b,s,2k] + c*x[b,s,2k+1]
// c = cos(s * 10000^(-2k/128)), s = sin(...)  with position index s = arange(SEQ)
// (the reference overwrites token_positions with arange, so d_in[1] and the
// dense d_in[2] rot buffer are both unused — we recompute the 2 MB cos/sin table).

#define ROPE_DK    128
#define ROPE_HALF  64     // d_k/2
#define ROPE_SEQ   4096
#define ROPE_BATCH 32

// log2(10000) to double precision, baked as f32 constant
#define LOG2_THETA 13.287712379549449f

// ---- Phase 1: build compact [SEQ][128] table: tbl[s][2k]=cos, tbl[s][2k+1]=sin ----
__global__ void rope_build_table(float* __restrict__ tbl) {
    int t = blockIdx.x * blockDim.x + threadIdx.x;   // one thread per (s, k)
    if (t >= ROPE_SEQ * ROPE_HALF) return;
    int s = t >> 6;          // position
    int k = t & 63;          // pair index
    float ex  = (float)(2 * k) * (1.0f / (float)ROPE_DK);
    float inv = exp2f(-ex * LOG2_THETA);             // 10000^(-2k/128)
    float ang = (float)s * inv;
    float sn, cs;
    sincosf(ang, &sn, &cs);
    reinterpret_cast<float2*>(tbl)[t] = make_float2(cs, sn);
}

// ---- Phase 2: streaming rotate, one float4 (= 2 pairs) per iteration ----
__global__ void rope_apply(const float4* __restrict__ x,
                           const float4* __restrict__ tbl,
                           float4* __restrict__ out, int n4) {
    int idx    = blockIdx.x * blockDim.x + threadIdx.x;
    int stride = gridDim.x * blockDim.x;
    // per-batch row layout: 4096 positions * 32 float4/row -> table idx = idx mod 131072
    for (; idx < n4; idx += stride) {
        float4 t = tbl[idx & (ROPE_SEQ * 32 - 1)];   // (c_k0, s_k0, c_k1, s_k1) — L2-hot
        float4 v = x[idx];
        float4 o;
        o.x = t.x * v.x - t.y * v.y;
        o.y = t.y * v.x + t.x * v.y;
        o.z = t.z * v.z - t.w * v.w;
        o.w = t.w * v.z + t.z * v.w;
        out[idx] = o;
    }
}

// ---- Fallback (only if ws is too small): fused sincos + rotate, float2 per thread ----
__global__ void rope_fused(const float4* __restrict__ x,
                           float4* __restrict__ out, int n4) {
    int idx    = blockIdx.x * blockDim.x + threadIdx.x;
    int stride = gridDim.x * blockDim.x;
    for (; idx < n4; idx += stride) {
        int sd = idx & (ROPE_SEQ * 32 - 1);
        int s  = sd >> 5;
        int d4 = sd & 31;                 // float4 index within row; pairs 2*d4, 2*d4+1
        float4 v = x[idx];
        float4 o;
        #pragma unroll
        for (int half = 0; half < 2; ++half) {
            int k = 2 * d4 + half;
            float ex  = (float)(2 * k) * (1.0f / (float)ROPE_DK);
            float inv = exp2f(-ex * LOG2_THETA);
            float ang = (float)s * inv;
            float sn, cs;
            sincosf(ang, &sn, &cs);
            if (half == 0) { o.x = cs * v.x - sn * v.y; o.y = sn * v.x + cs * v.y; }
            else           { o.z = cs * v.z - sn * v.w; o.w = sn * v.z + cs * v.w; }
        }
        out[idx] = o;
    }
}

extern "C" void kernel_launch(void* const* d_in, const int* in_sizes, int n_in,
                              void* d_out, int out_size, void* d_ws, size_t ws_size,
                              hipStream_t stream) {
    const float* x = (const float*)d_in[0];      // [32, 4096, 128] f32
    // d_in[1] token_positions: unused (reference overwrites with arange)
    // d_in[2] rot: unused (recomputed compactly)
    float* out = (float*)d_out;

    const int n4 = ROPE_BATCH * ROPE_SEQ * (ROPE_DK / 4);   // 4,194,304 float4s
    const size_t tbl_bytes = (size_t)ROPE_SEQ * ROPE_DK * sizeof(float);  // 2 MiB

    if (ws_size >= tbl_bytes) {
        float* tbl = (float*)d_ws;
        int nt = ROPE_SEQ * ROPE_HALF;                       // 262,144
        rope_build_table<<<(nt + 255) / 256, 256, 0, stream>>>(tbl);
        rope_apply<<<2048, 256, 0, stream>>>((const float4*)x, (const float4*)tbl,
                                             (float4*)out, n4);
    } else {
        rope_fused<<<2048, 256, 0, stream>>>((const float4*)x, (float4*)out, n4);
    }
}

// Round 4
// 346.156 us; speedup vs baseline: 1.0215x; 1.0215x over previous
//
#include <hip/hip_runtime.h>

// RoPE: out[b,s,2k]   = c*x[b,s,2k] - s*x[b,s,2k+1]
//       out[b,s,2k+1] = s*x[b,s,2k] + c*x[b,s,2k+1]
// c = cos(s * 10000^(-2k/128)), s = sin(...), position s = arange(SEQ)
// (reference overwrites token_positions with arange; the dense rot buffer is unused).
//
// Single fused kernel. Grid is sized so that total threads (524,288) is a
// multiple of the per-batch-row float4 count (4096*32 = 131,072); therefore
// each thread's (position, pair-index) is INVARIANT across its 8 grid-stride
// iterations -> compute sincos ONCE per thread, fully hidden under the
// 134 MB streaming traffic. No workspace, no table, no second kernel.
//
// Note: nontemporal builtins need clang native vectors, not HIP_vector_type.

typedef float f32x4 __attribute__((ext_vector_type(4)));

#define ROPE_DK    128
#define ROPE_SEQ   4096
#define ROPE_BATCH 32
#define LOG2_THETA 13.287712379549449f   // log2(10000)

__global__ __launch_bounds__(256) void rope_fused(const f32x4* __restrict__ x,
                                                  f32x4* __restrict__ out) {
    constexpr int n4   = ROPE_BATCH * ROPE_SEQ * (ROPE_DK / 4);  // 4,194,304
    constexpr int rowm = ROPE_SEQ * 32 - 1;                      // 131,071
    const int tid    = blockIdx.x * 256 + threadIdx.x;
    const int stride = gridDim.x * 256;                          // 524,288 ≡ 0 mod 131,072

    // Loop-invariant (position, pair) for this thread:
    const int   sd  = tid & rowm;
    const float pos = (float)(sd >> 5);          // position index s
    const int   d4  = sd & 31;                   // float4 index within the 128-wide row
    // pair indices k0 = 2*d4, k1 = 2*d4+1 ; inv_theta = 10000^(-2k/128)
    float sn0, cs0, sn1, cs1;
    {
        const float k0   = (float)(2 * d4);
        const float k1   = k0 + 1.0f;
        const float inv0 = exp2f(-(2.0f * k0) * (LOG2_THETA / 128.0f));
        const float inv1 = exp2f(-(2.0f * k1) * (LOG2_THETA / 128.0f));
        sincosf(pos * inv0, &sn0, &cs0);
        sincosf(pos * inv1, &sn1, &cs1);
    }

    for (int idx = tid; idx < n4; idx += stride) {
        f32x4 v = __builtin_nontemporal_load(&x[idx]);
        f32x4 o;
        o.x = cs0 * v.x - sn0 * v.y;
        o.y = sn0 * v.x + cs0 * v.y;
        o.z = cs1 * v.z - sn1 * v.w;
        o.w = sn1 * v.z + cs1 * v.w;
        __builtin_nontemporal_store(o, &out[idx]);
    }
}

extern "C" void kernel_launch(void* const* d_in, const int* in_sizes, int n_in,
                              void* d_out, int out_size, void* d_ws, size_t ws_size,
                              hipStream_t stream) {
    const f32x4* x   = (const f32x4*)d_in[0];   // [32, 4096, 128] f32
    f32x4*       out = (f32x4*)d_out;
    // d_in[1] (token_positions) and d_in[2] (rot) intentionally unused.
    rope_fused<<<2048, 256, 0, stream>>>(x, out);
}